// Round 13
// baseline (92.331 us; speedup 1.0000x reference)
//
#include <hip/hip_runtime.h>
#include <hip/hip_bf16.h>

#define BB 512
#define TT 2048
#define SS 128
#define LL 64
#define PP (TT - LL + 1)   // 1985

#define XF_N  2128                // staged fp32 x (zero-padded past 2048)
#define XCP_W 530                 // 8B words per shifted copy; (2*530)%32==4 ->
                                  // copies start 4 banks apart => reads tile 32 banks
#define SH_ROW_SHORTS 72          // 64 data + 8 pad shorts (row stride 144 B)

#define REP 3                     // DIAGNOSTIC: repeat main loop to make this
                                  // dispatch outrank the 40us ws-fills in top-5.
                                  // Identical result each rep (max is idempotent).

typedef __attribute__((ext_vector_type(8))) short    short8;
typedef __attribute__((ext_vector_type(4))) float    float4v;
typedef __attribute__((ext_vector_type(4))) unsigned uint4v;

__device__ __forceinline__ unsigned f2bf1(float f) {
  union { float f; unsigned u; } v; v.f = f;
  return (v.u + 0x7FFFu + ((v.u >> 16) & 1u)) >> 16;   // RNE fp32->bf16
}

// ---- single fused kernel: 1 block (512 thr, 8 waves) per sample ----
// R13 = R11 kernel with REP x main loop (visibility diagnostic).
__global__ __launch_bounds__(512)
void shapelet_fused(const float* __restrict__ x, const float* __restrict__ shg,
                    float* __restrict__ out) {
  __shared__ __align__(16) float xf[XF_N];
  __shared__ __align__(16) unsigned long long xcp[8][XCP_W];
  __shared__ float c0h[2048];
  __shared__ __align__(16) short shb[SS * SH_ROW_SHORTS];
  __shared__ float s2cl[SS];
  __shared__ float wred[8 * 64];

  const int t = threadIdx.x;
  const int b = blockIdx.x;
  const int lane = t & 63, wave = t >> 6;
  const int n = lane & 15, q = lane >> 4;
  const int shalf = wave & 1, pq = wave >> 1;

  // ---- stage x[b] (8 KB) into LDS, zero-pad to XF_N ----
  for (int idx = t; idx < XF_N / 4; idx += 512) {
    const int g0 = 4 * idx;
    float4v v = {0.f, 0.f, 0.f, 0.f};
    if (g0 + 3 < TT) v = *(const float4v*)(x + (size_t)b * TT + g0);
    *(float4v*)(xf + 4 * idx) = v;
  }

  // ---- shapelet prep (redundant per block; 32 KB, L2-resident) ----
  {
    const int s = t >> 2, part = t & 3;
    const float4v* sp = (const float4v*)(shg + s * LL + part * 16);
    float4v r0 = sp[0], r1 = sp[1], r2 = sp[2], r3 = sp[3];
    float sum = 0.f, sq = 0.f;
    #pragma unroll
    for (int k = 0; k < 4; ++k) {
      const float4v rv = (k == 0) ? r0 : (k == 1) ? r1 : (k == 2) ? r2 : r3;
      sum += (rv[0] + rv[1]) + (rv[2] + rv[3]);
      sq = fmaf(rv[0], rv[0], sq); sq = fmaf(rv[1], rv[1], sq);
      sq = fmaf(rv[2], rv[2], sq); sq = fmaf(rv[3], rv[3], sq);
    }
    sum += __shfl_xor(sum, 1); sum += __shfl_xor(sum, 2);
    sq  += __shfl_xor(sq, 1);  sq  += __shfl_xor(sq, 2);
    const float mean = sum * (1.f / 64.f);

    unsigned pk[8];
    #pragma unroll
    for (int k = 0; k < 4; ++k) {
      const float4v rv = (k == 0) ? r0 : (k == 1) ? r1 : (k == 2) ? r2 : r3;
      pk[2 * k]     = f2bf1(rv[0] - mean) | (f2bf1(rv[1] - mean) << 16);
      pk[2 * k + 1] = f2bf1(rv[2] - mean) | (f2bf1(rv[3] - mean) << 16);
    }
    unsigned* shbw = (unsigned*)shb;
    const int dw = s * (SH_ROW_SHORTS / 2) + part * 8;   // 16B aligned
    uint4v w0v = {pk[0], pk[1], pk[2], pk[3]};
    uint4v w1v = {pk[4], pk[5], pk[6], pk[7]};
    *(uint4v*)(shbw + dw) = w0v;
    *(uint4v*)(shbw + dw + 4) = w1v;
    if (part == 0) s2cl[s] = sq;      // s2c = raw sum of squares
  }

  __syncthreads();

  // ---- B fragments from LDS shapelets ----
  short8 bf[2][4];
  #pragma unroll
  for (int st = 0; st < 4; ++st) {
    const int row = shalf * 64 + st * 16 + n;
    bf[0][st] = *(const short8*)(shb + row * SH_ROW_SHORTS + q * 8);
    bf[1][st] = *(const short8*)(shb + row * SH_ROW_SHORTS + 32 + q * 8);
  }

  // ---- build 8 element-shifted bf16 copies of xf ----
  for (int w = t; w < XCP_W; w += 512) {
    const float4v* xf4 = (const float4v*)xf;
    float4v A = xf4[w], Bv = xf4[w + 1], Cv = xf4[w + 2];
    unsigned bfx[11];
    #pragma unroll
    for (int k = 0; k < 4; ++k) bfx[k] = f2bf1(A[k]);
    #pragma unroll
    for (int k = 0; k < 4; ++k) bfx[4 + k] = f2bf1(Bv[k]);
    #pragma unroll
    for (int k = 0; k < 3; ++k) bfx[8 + k] = f2bf1(Cv[k]);
    #pragma unroll
    for (int c = 0; c < 8; ++c) {
      unsigned long long pkw =
          (unsigned long long)bfx[c] |
          ((unsigned long long)bfx[c + 1] << 16) |
          ((unsigned long long)bfx[c + 2] << 32) |
          ((unsigned long long)bfx[c + 3] << 48);
      xcp[c][w] = pkw;
    }
  }

  // ---- window stats: thread t -> windows 4t..4t+3 (rolling, capped unroll) ----
  {
    const float4v* xf4 = (const float4v*)xf;
    float S = 0.f, Q = 0.f;
    float4v v0 = xf4[t];
    float4v vcur = v0;
    #pragma unroll 4
    for (int ch = 0; ch < 16; ++ch) {
      S += (vcur[0] + vcur[1]) + (vcur[2] + vcur[3]);
      Q = fmaf(vcur[0], vcur[0], Q); Q = fmaf(vcur[1], vcur[1], Q);
      Q = fmaf(vcur[2], vcur[2], Q); Q = fmaf(vcur[3], vcur[3], Q);
      vcur = xf4[t + ch + 1];           // after loop: vcur = xf4[t+16]
    }
    const float4v vN = vcur;
    const int p0s = 4 * t;
    #pragma unroll
    for (int r = 0; r < 4; ++r) {
      const bool valid = (p0s + r) < PP;
      const float c0 = Q - S * S * (1.f / 64.f);
      c0h[p0s + r] = valid ? (-0.5f * c0) : -INFINITY;
      if (r < 3) {
        const float vin = vN[r], vout = v0[r];
        S += vin - vout;
        Q += fmaf(vin, vin, -vout * vout);
      }
    }
  }

  __syncthreads();

  // ---- main MFMA loop (xREP): single 16-p tile per iter, rolling A-ring ----
  const int cc = n & 7;
  const int lw = 2 * q + 2 * (n >> 3);          // even => aligned ds_read_b128
  const unsigned long long* xc = &xcp[cc][0];
  const int base = pq * 512;
  const int w0 = (base >> 2) + lw;

  float rmax[4];
  #pragma unroll
  for (int st = 0; st < 4; ++st) rmax[st] = -INFINITY;

  #pragma unroll 1
  for (int rep = 0; rep < REP; ++rep) {
    short8 h0 = *(const short8*)&xc[w0];          // frag(base,    kb0)
    short8 h1 = *(const short8*)&xc[w0 + 4];      // frag(base+16, kb0)

    #pragma unroll 2
    for (int mt = 0; mt < 32; ++mt) {
      const short8 l = *(const short8*)&xc[w0 + 4 * mt + 8];   // frag(p0, kb1)
      const float4v c0v = *(const float4v*)&c0h[base + 16 * mt + 4 * q];

      #pragma unroll
      for (int st = 0; st < 4; ++st) {
        float4v acc = __builtin_amdgcn_mfma_f32_16x16x32_bf16(h0, bf[0][st], c0v, 0, 0, 0);
        acc = __builtin_amdgcn_mfma_f32_16x16x32_bf16(l, bf[1][st], acc, 0, 0, 0);
        const float m01 = fmaxf(acc[0], acc[1]);
        const float m23 = fmaxf(acc[2], acc[3]);
        rmax[st] = fmaxf(rmax[st], fmaxf(m01, m23));
      }
      h0 = h1;          // frag(p0, kb1) == frag(p0+32, kb0)
      h1 = l;
    }
  }

  // ---- reduce: across q (shfl), across 4 pq-waves (LDS), write out ----
  #pragma unroll
  for (int st = 0; st < 4; ++st) {
    float v = rmax[st];
    v = fmaxf(v, __shfl_xor(v, 16));
    v = fmaxf(v, __shfl_xor(v, 32));
    if (q == 0) wred[wave * 64 + st * 16 + n] = v;
  }
  __syncthreads();

  if (t < SS) {
    const int g = t >> 6, k = t & 63;           // s = g*64 + k
    const float v = fmaxf(fmaxf(wred[(g) * 64 + k],     wred[(2 + g) * 64 + k]),
                          fmaxf(wred[(4 + g) * 64 + k], wred[(6 + g) * 64 + k]));
    const float d2 = fmaf(-2.f, v, s2cl[t]);
    out[(size_t)b * SS + t] = sqrtf(fmaxf(d2, 0.f));
  }
}

extern "C" void kernel_launch(void* const* d_in, const int* in_sizes, int n_in,
                              void* d_out, int out_size, void* d_ws, size_t ws_size,
                              hipStream_t stream) {
  const float* x  = (const float*)d_in[0];
  const float* sh = (const float*)d_in[1];
  float* out = (float*)d_out;
  shapelet_fused<<<dim3(BB), dim3(512), 0, stream>>>(x, sh, out);
}

// Round 14
// 72.265 us; speedup vs baseline: 1.2777x; 1.2777x over previous
//
#include <hip/hip_runtime.h>
#include <hip/hip_bf16.h>

#define BB 512
#define TT 2048
#define SS 128
#define LL 64
#define PP (TT - LL + 1)   // 1985

// ws float-offset layout:
//   [0, 131072)       partials: part[j*65536 + b*128 + s], j = 0,1
//   [131072, 131200)  s2c[s] = sum(scent^2) + 64*mean^2
//   byte 1048576..    centered bf16 shapelets, padded rows: 128 x 72 shorts
#define WS_PART 0
#define WS_S2C  131072
#define WS_SHB_BYTE 1048576
#define SH_ROW_SHORTS 72          // 64 data + 8 pad (row stride 144 B)

#define XF_N  1104                // staged fp32 elems per 1024-window strip
#define XCP_BUILD 272             // xcp words built (max word touched: 269)
#define XCP_W 274                 // row stride in 8B words; (2*274)%32==4 ->
                                  // copies start 4 banks apart (bank-balanced)

typedef __attribute__((ext_vector_type(8))) short  short8;
typedef __attribute__((ext_vector_type(4))) float  float4v;

__device__ __forceinline__ unsigned f2bf1(float f) {
  union { float f; unsigned u; } v; v.f = f;
  return (v.u + 0x7FFFu + ((v.u >> 16) & 1u)) >> 16;   // RNE fp32->bf16
}

// ---------- prep: center shapelets, bf16-pack (padded rows), s2c ----------
__global__ __launch_bounds__(64)
void prep_kernel(const float* __restrict__ shg, float* __restrict__ ws) {
  const int s = blockIdx.x, l = threadIdx.x;
  float v = shg[s * LL + l];
  float sum = v;
  #pragma unroll
  for (int off = 1; off < 64; off <<= 1) sum += __shfl_xor(sum, off);
  const float mean = sum * (1.f / 64.f);
  const float sc = v - mean;
  float sq = sc * sc;
  #pragma unroll
  for (int off = 1; off < 64; off <<= 1) sq += __shfl_xor(sq, off);

  unsigned bfu = f2bf1(sc);
  unsigned other = __shfl_down(bfu, 1);
  if ((l & 1) == 0) {
    unsigned* shbw = (unsigned*)((char*)ws + WS_SHB_BYTE);
    shbw[s * (SH_ROW_SHORTS / 2) + (l >> 1)] = bfu | (other << 16);
  }
  if (l == 0) ws[WS_S2C + s] = sq + 64.f * mean * mean;
}

// ---------- main: 2 j-halves/sample, 512 thr (8 waves), ~27.4 KB LDS ----------
// Occupancy target: 4 blocks/CU x 8 waves = 32 waves/CU (VGPR<=64, measured 52).
// wave w: shalf = w&1 (64 shapelets), pq = w>>1 (256 windows, 16 tiles).
// d2 = c0[p] + s2c[s] - 2*cross(x, scent); C-init = -c0/2; g = max(cross - c0/2).
__global__ __launch_bounds__(512)
void shapelet_main(const float* __restrict__ x, float* ws) {
  __shared__ __align__(16) float xf[XF_N];
  __shared__ __align__(16) unsigned long long xcp[8][XCP_W];
  __shared__ float c0h[1024];
  __shared__ float wred[8 * 64];

  const int t = threadIdx.x;
  const int bid = blockIdx.x;
  const int b = bid >> 1, j = bid & 1;
  const int pg = j * 1024;

  const int lane = t & 63, wave = t >> 6;
  const int n = lane & 15, q = lane >> 4;
  const int shalf = wave & 1, pq = wave >> 1;

  // ---- B fragments from global early (L2-resident; hides under staging) ----
  short8 bf[2][4];
  {
    const short* shb = (const short*)((const char*)ws + WS_SHB_BYTE);
    #pragma unroll
    for (int st = 0; st < 4; ++st) {
      const int row = shalf * 64 + st * 16 + n;
      bf[0][st] = *(const short8*)(shb + row * SH_ROW_SHORTS + q * 8);
      bf[1][st] = *(const short8*)(shb + row * SH_ROW_SHORTS + 32 + q * 8);
    }
  }

  // ---- stage x strip [pg, pg+XF_N) into LDS, zero-pad past TT ----
  if (t < XF_N / 4) {
    const int g0 = pg + 4 * t;
    float4v v = {0.f, 0.f, 0.f, 0.f};
    if (g0 + 3 < TT) {
      v = *(const float4v*)(x + (size_t)b * TT + g0);
    } else if (g0 < TT) {
      #pragma unroll
      for (int k = 0; k < 4; ++k) v[k] = (g0 + k < TT) ? x[(size_t)b * TT + g0 + k] : 0.f;
    }
    *(float4v*)(xf + 4 * t) = v;
  }

  __syncthreads();

  if (t < 256) {
    // ---- window stats (waves 0-3): thread t -> windows 4t..4t+3 ----
    const float4v* xf4 = (const float4v*)xf;
    float S = 0.f, Q = 0.f;
    float4v v0 = xf4[t];
    float4v vcur = v0;
    #pragma unroll 4
    for (int ch = 0; ch < 16; ++ch) {
      S += (vcur[0] + vcur[1]) + (vcur[2] + vcur[3]);
      Q = fmaf(vcur[0], vcur[0], Q); Q = fmaf(vcur[1], vcur[1], Q);
      Q = fmaf(vcur[2], vcur[2], Q); Q = fmaf(vcur[3], vcur[3], Q);
      vcur = xf4[t + ch + 1];           // after loop: vcur = xf4[t+16]
    }
    const float4v vN = vcur;
    const int p0s = 4 * t;
    #pragma unroll
    for (int r = 0; r < 4; ++r) {
      const bool valid = (pg + p0s + r) < PP;
      const float c0 = Q - S * S * (1.f / 64.f);
      c0h[p0s + r] = valid ? (-0.5f * c0) : -INFINITY;
      if (r < 3) {
        const float vin = vN[r], vout = v0[r];
        S += vin - vout;
        Q += fmaf(vin, vin, -vout * vout);
      }
    }
  } else {
    // ---- copy-build (waves 4-7): 8 element-shifted bf16 copies ----
    for (int w = t - 256; w < XCP_BUILD; w += 256) {
      const float4v* xf4 = (const float4v*)xf;
      float4v A = xf4[w], Bv = xf4[w + 1], Cv = xf4[w + 2];
      unsigned bfx[11];
      #pragma unroll
      for (int k = 0; k < 4; ++k) bfx[k] = f2bf1(A[k]);
      #pragma unroll
      for (int k = 0; k < 4; ++k) bfx[4 + k] = f2bf1(Bv[k]);
      #pragma unroll
      for (int k = 0; k < 3; ++k) bfx[8 + k] = f2bf1(Cv[k]);
      #pragma unroll
      for (int c = 0; c < 8; ++c) {
        unsigned long long pk =
            (unsigned long long)bfx[c] |
            ((unsigned long long)bfx[c + 1] << 16) |
            ((unsigned long long)bfx[c + 2] << 32) |
            ((unsigned long long)bfx[c + 3] << 48);
        xcp[c][w] = pk;
      }
    }
  }

  __syncthreads();

  // ---- main MFMA loop: 16 tiles of 16 windows, rolling 2-deep A-ring ----
  const int cc = n & 7;
  const int lw = 2 * q + 2 * (n >> 3);          // even => aligned ds_read_b128
  const unsigned long long* xc = &xcp[cc][0];
  const int base = pq * 256;
  const int w0 = (base >> 2) + lw;

  float rmax[4];
  #pragma unroll
  for (int st = 0; st < 4; ++st) rmax[st] = -INFINITY;

  short8 h0 = *(const short8*)&xc[w0];          // frag(base,    kb0)
  short8 h1 = *(const short8*)&xc[w0 + 4];      // frag(base+16, kb0)

  #pragma unroll 2
  for (int mt = 0; mt < 16; ++mt) {
    const short8 l = *(const short8*)&xc[w0 + 4 * mt + 8];   // frag(p0, kb1)
    const float4v c0v = *(const float4v*)&c0h[base + 16 * mt + 4 * q];

    #pragma unroll
    for (int st = 0; st < 4; ++st) {
      float4v acc = __builtin_amdgcn_mfma_f32_16x16x32_bf16(h0, bf[0][st], c0v, 0, 0, 0);
      acc = __builtin_amdgcn_mfma_f32_16x16x32_bf16(l, bf[1][st], acc, 0, 0, 0);
      // two v_max3: max3(a0,a1,rmax) then max3(a2,a3,that)
      rmax[st] = fmaxf(fmaxf(acc[2], acc[3]),
                       fmaxf(fmaxf(acc[0], acc[1]), rmax[st]));
    }
    h0 = h1;          // frag(p0, kb1) == frag(p0+32, kb0)
    h1 = l;
  }

  // ---- reduce: across q (shfl), across 4 pq-waves (LDS), write partial ----
  #pragma unroll
  for (int st = 0; st < 4; ++st) {
    float v = rmax[st];
    v = fmaxf(v, __shfl_xor(v, 16));
    v = fmaxf(v, __shfl_xor(v, 32));
    if (q == 0) wred[wave * 64 + st * 16 + n] = v;
  }
  __syncthreads();

  if (t < SS) {
    const int g = t >> 6, k = t & 63;           // s = g*64 + k; waves {g,g+2,g+4,g+6}
    const float v = fmaxf(fmaxf(wred[(g) * 64 + k],     wred[(2 + g) * 64 + k]),
                          fmaxf(wred[(4 + g) * 64 + k], wred[(6 + g) * 64 + k]));
    ws[WS_PART + (size_t)j * 65536 + (size_t)b * 128 + t] = v;
  }
}

// ---------- combine: max over 2 j-halves, d2 = s2c - 2g, sqrt ----------
__global__ __launch_bounds__(256)
void combine_kernel(const float* __restrict__ ws, float* __restrict__ out) {
  const int tid = blockIdx.x * 256 + threadIdx.x;   // 0 .. 65535
  const int s = tid & 127;
  const float g = fmaxf(ws[WS_PART + tid], ws[WS_PART + 65536 + tid]);
  const float d2 = fmaf(-2.f, g, ws[WS_S2C + s]);
  out[tid] = sqrtf(fmaxf(d2, 0.f));
}

extern "C" void kernel_launch(void* const* d_in, const int* in_sizes, int n_in,
                              void* d_out, int out_size, void* d_ws, size_t ws_size,
                              hipStream_t stream) {
  const float* x  = (const float*)d_in[0];
  const float* sh = (const float*)d_in[1];
  float* out = (float*)d_out;
  float* ws = (float*)d_ws;
  prep_kernel<<<dim3(SS), dim3(64), 0, stream>>>(sh, ws);
  shapelet_main<<<dim3(BB * 2), dim3(512), 0, stream>>>(x, ws);
  combine_kernel<<<dim3(256), dim3(256), 0, stream>>>(ws, out);
}

// Round 15
// 70.459 us; speedup vs baseline: 1.3104x; 1.0256x over previous
//
#include <hip/hip_runtime.h>
#include <hip/hip_bf16.h>

#define BB 512
#define TT 2048
#define SS 128
#define LL 64
#define PP (TT - LL + 1)   // 1985

#define XF_N  2128                // staged fp32 x (zero-padded past 2048)
#define XCP_W 530                 // 8B words per shifted copy; (2*530)%32==4 ->
                                  // copies start 4 banks apart => reads tile 32 banks
#define SH_ROW_SHORTS 72          // 64 data + 8 pad shorts (row stride 144 B)

typedef __attribute__((ext_vector_type(8))) short    short8;
typedef __attribute__((ext_vector_type(4))) float    float4v;
typedef __attribute__((ext_vector_type(4))) unsigned uint4v;

__device__ __forceinline__ unsigned f2bf1(float f) {
  union { float f; unsigned u; } v; v.f = f;
  return (v.u + 0x7FFFu + ((v.u >> 16) & 1u)) >> 16;   // RNE fp32->bf16
}

// ---- single fused kernel: 1 block (1024 thr, 16 waves) per sample ----
// Occupancy: LDS ~72 KB -> 2 blocks/CU; 16 waves/block -> 32 waves/CU (100%)
// REQUIRES VGPR <= 64 (R13 measured 52 for this loop).
// wave w: shalf = w&1 (64 shapelets), pq = w>>1 (256 windows, 16 tiles).
// d2 = c0[p] + s2c[s] - 2*cross(x, centered_s); C-init = -c0/2;
// g = max_p(cross - c0/2); out = sqrt(s2c - 2g), s2c = raw sum(s^2).
__global__ __launch_bounds__(1024)
void shapelet_fused(const float* __restrict__ x, const float* __restrict__ shg,
                    float* __restrict__ out) {
  __shared__ __align__(16) float xf[XF_N];
  __shared__ __align__(16) unsigned long long xcp[8][XCP_W];
  __shared__ float c0h[2048];
  __shared__ __align__(16) short shb[SS * SH_ROW_SHORTS];
  __shared__ float s2cl[SS];
  __shared__ float wred[16 * 64];

  const int t = threadIdx.x;
  const int b = blockIdx.x;
  const int lane = t & 63, wave = t >> 6;
  const int n = lane & 15, q = lane >> 4;
  const int shalf = wave & 1, pq = wave >> 1;

  // ---- phase 1: threads <532 stage x[b]; threads >=512 do shapelet prep ----
  if (t < XF_N / 4) {
    const int g0 = 4 * t;
    float4v v = {0.f, 0.f, 0.f, 0.f};
    if (g0 + 3 < TT) v = *(const float4v*)(x + (size_t)b * TT + g0);
    *(float4v*)(xf + 4 * t) = v;
  }
  if (t >= 512) {
    // shapelet prep: row s = th>>2, quarter part = th&3 (16 floats)
    const int th = t - 512;
    const int s = th >> 2, part = th & 3;
    const float4v* sp = (const float4v*)(shg + s * LL + part * 16);
    float4v r0 = sp[0], r1 = sp[1], r2 = sp[2], r3 = sp[3];
    float sum = 0.f, sq = 0.f;
    #pragma unroll
    for (int k = 0; k < 4; ++k) {
      const float4v rv = (k == 0) ? r0 : (k == 1) ? r1 : (k == 2) ? r2 : r3;
      sum += (rv[0] + rv[1]) + (rv[2] + rv[3]);
      sq = fmaf(rv[0], rv[0], sq); sq = fmaf(rv[1], rv[1], sq);
      sq = fmaf(rv[2], rv[2], sq); sq = fmaf(rv[3], rv[3], sq);
    }
    sum += __shfl_xor(sum, 1); sum += __shfl_xor(sum, 2);
    sq  += __shfl_xor(sq, 1);  sq  += __shfl_xor(sq, 2);
    const float mean = sum * (1.f / 64.f);

    unsigned pk[8];
    #pragma unroll
    for (int k = 0; k < 4; ++k) {
      const float4v rv = (k == 0) ? r0 : (k == 1) ? r1 : (k == 2) ? r2 : r3;
      pk[2 * k]     = f2bf1(rv[0] - mean) | (f2bf1(rv[1] - mean) << 16);
      pk[2 * k + 1] = f2bf1(rv[2] - mean) | (f2bf1(rv[3] - mean) << 16);
    }
    unsigned* shbw = (unsigned*)shb;
    const int dw = s * (SH_ROW_SHORTS / 2) + part * 8;   // 16B aligned
    uint4v w0v = {pk[0], pk[1], pk[2], pk[3]};
    uint4v w1v = {pk[4], pk[5], pk[6], pk[7]};
    *(uint4v*)(shbw + dw) = w0v;
    *(uint4v*)(shbw + dw + 4) = w1v;
    if (part == 0) s2cl[s] = sq;      // s2c = raw sum of squares
  }

  __syncthreads();

  // ---- B fragments from LDS shapelets (all threads) ----
  short8 bf[2][4];
  #pragma unroll
  for (int st = 0; st < 4; ++st) {
    const int row = shalf * 64 + st * 16 + n;
    bf[0][st] = *(const short8*)(shb + row * SH_ROW_SHORTS + q * 8);
    bf[1][st] = *(const short8*)(shb + row * SH_ROW_SHORTS + 32 + q * 8);
  }

  // ---- phase 2: waves 0-7 window stats; waves 8-15 copy-build ----
  if (t < 512) {
    // window stats: thread t -> windows 4t..4t+3 (rolling, capped unroll)
    const float4v* xf4 = (const float4v*)xf;
    float S = 0.f, Q = 0.f;
    float4v v0 = xf4[t];
    float4v vcur = v0;
    #pragma unroll 4
    for (int ch = 0; ch < 16; ++ch) {
      S += (vcur[0] + vcur[1]) + (vcur[2] + vcur[3]);
      Q = fmaf(vcur[0], vcur[0], Q); Q = fmaf(vcur[1], vcur[1], Q);
      Q = fmaf(vcur[2], vcur[2], Q); Q = fmaf(vcur[3], vcur[3], Q);
      vcur = xf4[t + ch + 1];           // after loop: vcur = xf4[t+16]
    }
    const float4v vN = vcur;
    const int p0s = 4 * t;
    #pragma unroll
    for (int r = 0; r < 4; ++r) {
      const bool valid = (p0s + r) < PP;
      const float c0 = Q - S * S * (1.f / 64.f);
      c0h[p0s + r] = valid ? (-0.5f * c0) : -INFINITY;
      if (r < 3) {
        const float vin = vN[r], vout = v0[r];
        S += vin - vout;
        Q += fmaf(vin, vin, -vout * vout);
      }
    }
  } else {
    // copy-build: 8 element-shifted bf16 copies; words t-512 and t (coverage 0..529)
    for (int w = t - 512; w < XCP_W; w += 512) {
      const float4v* xf4 = (const float4v*)xf;
      float4v A = xf4[w], Bv = xf4[w + 1], Cv = xf4[w + 2];
      unsigned bfx[11];
      #pragma unroll
      for (int k = 0; k < 4; ++k) bfx[k] = f2bf1(A[k]);
      #pragma unroll
      for (int k = 0; k < 4; ++k) bfx[4 + k] = f2bf1(Bv[k]);
      #pragma unroll
      for (int k = 0; k < 3; ++k) bfx[8 + k] = f2bf1(Cv[k]);
      #pragma unroll
      for (int c = 0; c < 8; ++c) {
        unsigned long long pkw =
            (unsigned long long)bfx[c] |
            ((unsigned long long)bfx[c + 1] << 16) |
            ((unsigned long long)bfx[c + 2] << 32) |
            ((unsigned long long)bfx[c + 3] << 48);
        xcp[c][w] = pkw;
      }
    }
  }

  __syncthreads();

  // ---- main MFMA loop: 16 tiles of 16 windows, rolling 2-deep A-ring ----
  const int cc = n & 7;
  const int lw = 2 * q + 2 * (n >> 3);          // even => aligned ds_read_b128
  const unsigned long long* xc = &xcp[cc][0];
  const int base = pq * 256;
  const int w0 = (base >> 2) + lw;

  float rmax[4];
  #pragma unroll
  for (int st = 0; st < 4; ++st) rmax[st] = -INFINITY;

  short8 h0 = *(const short8*)&xc[w0];          // frag(base,    kb0)
  short8 h1 = *(const short8*)&xc[w0 + 4];      // frag(base+16, kb0)

  #pragma unroll 2
  for (int mt = 0; mt < 16; ++mt) {
    const short8 l = *(const short8*)&xc[w0 + 4 * mt + 8];   // frag(p0, kb1)
    const float4v c0v = *(const float4v*)&c0h[base + 16 * mt + 4 * q];

    #pragma unroll
    for (int st = 0; st < 4; ++st) {
      float4v acc = __builtin_amdgcn_mfma_f32_16x16x32_bf16(h0, bf[0][st], c0v, 0, 0, 0);
      acc = __builtin_amdgcn_mfma_f32_16x16x32_bf16(l, bf[1][st], acc, 0, 0, 0);
      rmax[st] = fmaxf(fmaxf(acc[2], acc[3]),
                       fmaxf(fmaxf(acc[0], acc[1]), rmax[st]));   // v_max3 pair
    }
    h0 = h1;          // frag(p0, kb1) == frag(p0+32, kb0)
    h1 = l;
  }

  // ---- reduce: across q (shfl), across 8 pq-waves per shalf (LDS) ----
  #pragma unroll
  for (int st = 0; st < 4; ++st) {
    float v = rmax[st];
    v = fmaxf(v, __shfl_xor(v, 16));
    v = fmaxf(v, __shfl_xor(v, 32));
    if (q == 0) wred[wave * 64 + st * 16 + n] = v;
  }
  __syncthreads();

  if (t < SS) {
    const int g = t >> 6, k = t & 63;           // s = g*64 + k; waves 2*pq+g
    float v = -INFINITY;
    #pragma unroll
    for (int pqi = 0; pqi < 8; ++pqi)
      v = fmaxf(v, wred[(2 * pqi + g) * 64 + k]);
    const float d2 = fmaf(-2.f, v, s2cl[t]);
    out[(size_t)b * SS + t] = sqrtf(fmaxf(d2, 0.f));
  }
}

extern "C" void kernel_launch(void* const* d_in, const int* in_sizes, int n_in,
                              void* d_out, int out_size, void* d_ws, size_t ws_size,
                              hipStream_t stream) {
  const float* x  = (const float*)d_in[0];
  const float* sh = (const float*)d_in[1];
  float* out = (float*)d_out;
  shapelet_fused<<<dim3(BB), dim3(1024), 0, stream>>>(x, sh, out);
}